// Round 12
// baseline (82.173 us; speedup 1.0000x reference)
//
#include <hip/hip_runtime.h>
#include <math.h>

// Problem shape (fixed by reference setup_inputs):
//   feature_map: (B=8, D=256, H=128, W=128) fp32
//   para_code:   (8, 256)
//   W1 (256,256) b1(256) | Ws (256,256) bs(256) | Wr (256,256) br(256)
//   Wt (256,512) bt(512)
// Output: (8, 256, 128, 128) fp32

#define B_  8
#define D_  256
#define H_  128
#define W_  128
#define PC_ 256
#define PI_F 3.14159f
#define LPU_ 130  // padded bf16 LDS row stride (ushorts) = 65 dwords/row;
                  // 65 % 32 == 1 -> row-step gathers conflict-free.

// ------------- Kernel 1: fused p = relu(para@W1+b1) -> heads ----------------
__global__ void k_params(const float* __restrict__ para,
                         const float* __restrict__ W1, const float* __restrict__ b1,
                         const float* __restrict__ Ws, const float* __restrict__ bs,
                         const float* __restrict__ Wr, const float* __restrict__ br,
                         const float* __restrict__ Wt, const float* __restrict__ bt,
                         float* __restrict__ sc_o, float* __restrict__ c_o,
                         float* __restrict__ s_o,  float* __restrict__ tx_o,
                         float* __restrict__ ty_o) {
    __shared__ float sp[PC_];   // para row
    __shared__ float pp[PC_];   // relu'd hidden
    const int b = blockIdx.x;
    const int which = blockIdx.y;
    const int d = threadIdx.x;
    sp[d] = para[b * PC_ + d];
    __syncthreads();

    float acc = b1[d];
#pragma unroll 8
    for (int k = 0; k < PC_; ++k) {
        acc = fmaf(sp[k], W1[k * PC_ + d], acc);
    }
    pp[d] = fmaxf(acc, 0.0f);
    __syncthreads();

    const int o = b * D_ + d;
    if (which == 0) {
        float as = bs[d];
        float ar = br[d];
#pragma unroll 8
        for (int k = 0; k < PC_; ++k) {
            const float pk = pp[k];
            as = fmaf(pk, Ws[k * PC_ + d], as);
            ar = fmaf(pk, Wr[k * PC_ + d], ar);
        }
        const float scale = 2.0f / (1.0f + expf(-as));      // sigmoid * 2
        const float ang   = tanhf(ar) * PI_F;
        sc_o[o] = scale;
        c_o[o]  = cosf(ang);
        s_o[o]  = sinf(ang);
    } else {
        const float2* __restrict__ Wt2 = (const float2*)Wt;  // (256,256) float2
        float t0 = bt[2 * d];
        float t1 = bt[2 * d + 1];
#pragma unroll 8
        for (int k = 0; k < PC_; ++k) {
            const float pk = pp[k];
            const float2 wt = Wt2[k * PC_ + d];
            t0 = fmaf(pk, wt.x, t0);
            t1 = fmaf(pk, wt.y, t1);
        }
        tx_o[o] = tanhf(t0);
        ty_o[o] = tanhf(t1);
    }
}

// bf16 round-to-nearest-even (values are finite normals; no NaN path needed)
__device__ __forceinline__ unsigned short bf16_rne(float f) {
    unsigned int u = __float_as_uint(f);
    u += 0x7FFFu + ((u >> 16) & 1u);
    return (unsigned short)(u >> 16);
}

// ------------- Kernel 2: affine grid-sample via bf16 LDS plane --------------
// Round-11 shell (512 thr, 1 plane/block, bf16 33.5KB LDS -> 4 blocks/CU,
// 32 waves/CU). This round: (a) dword-pair gathers — per pixel-row read the
// 2 dwords containing ushorts x0,x0+1 (row stride = 65 dwords exactly), so
// one ds_read2_b32 pair per row: 2 LDS instrs/px instead of 4; decode by
// parity funnel-shift (v_alignbit). (b) start-stagger: co-resident blocks
// begin offset by (bid&3)*~1.7us so stage bursts of one block overlap
// compute of the others (phase-sum model: aligned phases = the ~84us wall).
__global__ __launch_bounds__(512, 8)
void k_sample(const float* __restrict__ fm,
              const float* __restrict__ sc_a, const float* __restrict__ c_a,
              const float* __restrict__ s_a,  const float* __restrict__ tx_a,
              const float* __restrict__ ty_a,
              float* __restrict__ out) {
    __shared__ unsigned short lds[129 * LPU_];   // 33,540 B -> 4 blocks/CU

    const int plane = blockIdx.x;                // 0 .. B_*D_-1
    const float* __restrict__ img = fm + (size_t)plane * (H_ * W_);
    float* __restrict__ op = out + (size_t)plane * (H_ * W_);
    const int tid = threadIdx.x;

    // ---- start stagger: de-phase the 4 co-resident blocks (~1.7us steps) ---
    {
        const int ph = plane & 3;
#pragma unroll 1
        for (int i = 0; i < ph; ++i) __builtin_amdgcn_s_sleep(64);
    }

    // ---- stage plane -> bf16 padded LDS (float4 loads, packed b32 writes) --
    {
        const float4* __restrict__ src = (const float4*)img;
#pragma unroll
        for (int j = 0; j < 8; ++j) {
            const int e4 = j * 512 + tid;        // float4 index 0..4095
            const float4 v = src[e4];
            const int h = e4 >> 5;               // (e4*4) >> 7
            const int w = (e4 & 31) * 4;
            unsigned int lo = (unsigned int)bf16_rne(v.x) |
                              ((unsigned int)bf16_rne(v.y) << 16);
            unsigned int hi = (unsigned int)bf16_rne(v.z) |
                              ((unsigned int)bf16_rne(v.w) << 16);
            // (h*130 + w)*2 bytes: w % 4 == 0 -> 4B aligned
            unsigned int* dst = (unsigned int*)&lds[h * LPU_ + w];
            dst[0] = lo;
            dst[1] = hi;
        }
    }
    // zero pads: col 128 of rows 0..128, and all of row 128 (taps read x0+1 /
    // y0+1 unconditionally; their weights are exactly 0 at the border)
    if (tid < H_ + 1)  lds[tid * LPU_ + W_] = 0;
    if (tid < LPU_)    lds[H_ * LPU_ + tid] = 0;
    if (tid == 0)      lds[129 * LPU_ - 1] = 0;  // last ushort (row128,col129)

    const float sc = sc_a[plane];
    const float cc = c_a[plane];
    const float ss = s_a[plane];
    const float tx = tx_a[plane];
    const float ty = ty_a[plane];

    // Fold normalized->pixel mapping: x = w*ax + h*bx + cx (align_corners=F):
    const float gstep = 2.0f / (float)(W_ - 1);
    const float k64 = (float)W_ * 0.5f;                  // 64
    const float ax =  cc * sc * gstep * k64;
    const float bx = -ss * sc * gstep * k64;
    const float cx = (tx - cc * sc + ss * sc + 1.0f) * k64 - 0.5f;
    const float ay =  ss * sc * gstep * k64;
    const float by =  cc * sc * gstep * k64;
    const float cy = (ty - ss * sc - cc * sc + 1.0f) * k64 - 0.5f;

    // Per-thread base pixel (h0 = tid>>7, w0 = tid&127); iteration adds
    // exactly 4 rows (512 threads / 128 cols): x_it = xb + it*dx4.
    const int h0 = tid >> 7;
    const int w0 = tid & (W_ - 1);
    const float xb = fmaf((float)w0, ax, fmaf((float)h0, bx, cx));
    const float yb = fmaf((float)w0, ay, fmaf((float)h0, by, cy));
    const float dx4 = 4.0f * bx;
    const float dy4 = 4.0f * by;

    const unsigned int* __restrict__ Ud = (const unsigned int*)lds;  // dword view

    __syncthreads();

    // ---- 32 px/thread in 8 batches of 4 pixels ----
#pragma unroll
    for (int b4 = 0; b4 < 8; ++b4) {
        float wxv[4], wyv[4];
        unsigned int lo0[4], hi0[4], lo1[4], hi1[4];
        unsigned int shv[4];

        // phase A: addresses + issue all dword-pair taps (2x ds_read2 / px)
#pragma unroll
        for (int u = 0; u < 4; ++u) {
            const float it = (float)(b4 * 4 + u);
            float x = fmaf(it, dx4, xb);
            float y = fmaf(it, dy4, yb);
            x = fminf(fmaxf(x, 0.0f), (float)(W_ - 1));   // border padding
            y = fminf(fmaxf(y, 0.0f), (float)(H_ - 1));
            const float x0f = floorf(x);
            const float y0f = floorf(y);
            wxv[u] = x - x0f;
            wyv[u] = y - y0f;
            // ushort index, exact: y0f*130 + x0f <= 16637 < 2^24
            const int bu = (int)fmaf(y0f, (float)LPU_, x0f);
            const int dw = bu >> 1;
            shv[u] = (unsigned int)(bu & 1) << 4;
            lo0[u] = Ud[dw];          // row y0:  ushorts 2dw..2dw+1
            hi0[u] = Ud[dw + 1];      //          ushorts 2dw+2..2dw+3
            lo1[u] = Ud[dw + 65];     // row y0+1 (65 dwords = 130 ushorts)
            hi1[u] = Ud[dw + 66];
        }

        __builtin_amdgcn_sched_barrier(0);

        // phase B: parity funnel-shift decode + lerps + coalesced stores
#pragma unroll
        for (int u = 0; u < 4; ++u) {
            const unsigned int t =
                (unsigned int)((((unsigned long long)hi0[u] << 32) | lo0[u]) >> shv[u]);
            const unsigned int bq =
                (unsigned int)((((unsigned long long)hi1[u] << 32) | lo1[u]) >> shv[u]);
            const float v00 = __uint_as_float(t << 16);
            const float v01 = __uint_as_float(t & 0xFFFF0000u);
            const float v10 = __uint_as_float(bq << 16);
            const float v11 = __uint_as_float(bq & 0xFFFF0000u);
            const int px = (b4 * 4 + u) * 512 + tid;
            const float top = v00 + wxv[u] * (v01 - v00);
            const float bot = v10 + wxv[u] * (v11 - v10);
            op[px] = top + wyv[u] * (bot - top);
        }
    }
}

extern "C" void kernel_launch(void* const* d_in, const int* in_sizes, int n_in,
                              void* d_out, int out_size, void* d_ws, size_t ws_size,
                              hipStream_t stream) {
    const float* feature_map = (const float*)d_in[0];
    const float* para_code   = (const float*)d_in[1];
    const float* W1 = (const float*)d_in[2];
    const float* b1 = (const float*)d_in[3];
    const float* Ws = (const float*)d_in[4];
    const float* bs = (const float*)d_in[5];
    const float* Wr = (const float*)d_in[6];
    const float* br = (const float*)d_in[7];
    const float* Wt = (const float*)d_in[8];
    const float* bt = (const float*)d_in[9];
    float* out = (float*)d_out;

    // Workspace layout (floats): sc | c | s | tx | ty (each B_*D_)
    float* ws_f = (float*)d_ws;
    float* sc_a  = ws_f;
    float* c_a   = sc_a + B_ * D_;
    float* s_a   = c_a  + B_ * D_;
    float* tx_a  = s_a  + B_ * D_;
    float* ty_a  = tx_a + B_ * D_;

    k_params<<<dim3(B_, 2), PC_, 0, stream>>>(para_code, W1, b1, Ws, bs, Wr, br,
                                              Wt, bt, sc_a, c_a, s_a, tx_a, ty_a);
    k_sample<<<B_ * D_, 512, 0, stream>>>(feature_map, sc_a, c_a, s_a, tx_a, ty_a, out);
}

// Round 13
// 80.556 us; speedup vs baseline: 1.0201x; 1.0201x over previous
//
#include <hip/hip_runtime.h>
#include <math.h>

// Problem shape (fixed by reference setup_inputs):
//   feature_map: (B=8, D=256, H=128, W=128) fp32
//   para_code:   (8, 256)
//   W1 (256,256) b1(256) | Ws (256,256) bs(256) | Wr (256,256) br(256)
//   Wt (256,512) bt(512)
// Output: (8, 256, 128, 128) fp32

#define B_  8
#define D_  256
#define H_  128
#define W_  128
#define PC_ 256
#define PI_F 3.14159f
#define RS_ 129   // record-row stride in dwords; 129 % 32 == 1 -> row-step
                  // gathers hit consecutive banks (conflict-free for rotation)

// ------------- Kernel 1: fused p = relu(para@W1+b1) -> heads ----------------
__global__ void k_params(const float* __restrict__ para,
                         const float* __restrict__ W1, const float* __restrict__ b1,
                         const float* __restrict__ Ws, const float* __restrict__ bs,
                         const float* __restrict__ Wr, const float* __restrict__ br,
                         const float* __restrict__ Wt, const float* __restrict__ bt,
                         float* __restrict__ sc_o, float* __restrict__ c_o,
                         float* __restrict__ s_o,  float* __restrict__ tx_o,
                         float* __restrict__ ty_o) {
    __shared__ float sp[PC_];   // para row
    __shared__ float pp[PC_];   // relu'd hidden
    const int b = blockIdx.x;
    const int which = blockIdx.y;
    const int d = threadIdx.x;
    sp[d] = para[b * PC_ + d];
    __syncthreads();

    float acc = b1[d];
#pragma unroll 8
    for (int k = 0; k < PC_; ++k) {
        acc = fmaf(sp[k], W1[k * PC_ + d], acc);
    }
    pp[d] = fmaxf(acc, 0.0f);
    __syncthreads();

    const int o = b * D_ + d;
    if (which == 0) {
        float as = bs[d];
        float ar = br[d];
#pragma unroll 8
        for (int k = 0; k < PC_; ++k) {
            const float pk = pp[k];
            as = fmaf(pk, Ws[k * PC_ + d], as);
            ar = fmaf(pk, Wr[k * PC_ + d], ar);
        }
        const float scale = 2.0f / (1.0f + expf(-as));      // sigmoid * 2
        const float ang   = tanhf(ar) * PI_F;
        sc_o[o] = scale;
        c_o[o]  = cosf(ang);
        s_o[o]  = sinf(ang);
    } else {
        const float2* __restrict__ Wt2 = (const float2*)Wt;  // (256,256) float2
        float t0 = bt[2 * d];
        float t1 = bt[2 * d + 1];
#pragma unroll 8
        for (int k = 0; k < PC_; ++k) {
            const float pk = pp[k];
            const float2 wt = Wt2[k * PC_ + d];
            t0 = fmaf(pk, wt.x, t0);
            t1 = fmaf(pk, wt.y, t1);
        }
        tx_o[o] = tanhf(t0);
        ty_o[o] = tanhf(t1);
    }
}

// pack {bf16(a) lo, bf16(b) hi} in one instruction (gfx950 VOP3, no builtin)
__device__ __forceinline__ unsigned int cvt_pk_bf16(float a, float b) {
    unsigned int d;
    asm("v_cvt_pk_bf16_f32 %0, %1, %2" : "=v"(d) : "v"(a), "v"(b));
    return d;
}

// ------------- Kernel 2: affine grid-sample via bf16 record LDS -------------
// Rounds 3-12: seven structures land 78-94us; pipe sums say LDS (38%) is the
// largest term on the per-pixel dependent chain. This round halves it:
// LDS holds RECORDS rec[y][x] = pack(bf16 v(y,x) lo, bf16 v(y+1,x) hi) —
// one dword per pixel position. A bilinear sample needs records (y0,x0) and
// (y0,x0+1) = ADJACENT dwords = ONE ds_read2_b32 for all 4 taps (was 2+
// instrs). Decode: 2 shl + 2 and. Staging: each thread builds its record
// rows from value rows r, min(r+1,127) (duplicate row read served by L1/L2,
// not HBM) packed via v_cvt_pk_bf16_f32 (1 VALU/record). 66KB -> 2 blocks/CU.
// Output stores nontemporal: don't evict the L3-resident input with 131MB
// of write allocations.
__global__ __launch_bounds__(512, 4)
void k_sample(const float* __restrict__ fm,
              const float* __restrict__ sc_a, const float* __restrict__ c_a,
              const float* __restrict__ s_a,  const float* __restrict__ tx_a,
              const float* __restrict__ ty_a,
              float* __restrict__ out) {
    __shared__ unsigned int rec[H_ * RS_];       // 128 x 129 dwords = 66,048 B

    const int plane = blockIdx.x;                // 0 .. B_*D_-1
    const float* __restrict__ img = fm + (size_t)plane * (H_ * W_);
    float* __restrict__ op = out + (size_t)plane * (H_ * W_);
    const int tid = threadIdx.x;

    // ---- stage: build record rows (4 threads per record row) ----
    {
        const int r   = tid >> 2;                 // record row 0..127
        const int sg  = (tid & 3) * 8;            // float4 index within row
        const float4* __restrict__ s0 = (const float4*)(img + r * W_);
        const float4* __restrict__ s1 = (const float4*)(img + min(r + 1, H_ - 1) * W_);
        unsigned int* __restrict__ dst = &rec[r * RS_ + sg * 4];
#pragma unroll
        for (int j = 0; j < 8; ++j) {
            const float4 a = s0[sg + j];
            const float4 b = s1[sg + j];
            dst[j * 4 + 0] = cvt_pk_bf16(a.x, b.x);
            dst[j * 4 + 1] = cvt_pk_bf16(a.y, b.y);
            dst[j * 4 + 2] = cvt_pk_bf16(a.z, b.z);
            dst[j * 4 + 3] = cvt_pk_bf16(a.w, b.w);
        }
    }
    // x-pad: record col 128 of every record row = 0 (read when x0=127 with
    // weight exactly 0)
    if (tid < H_) rec[tid * RS_ + W_] = 0;

    const float sc = sc_a[plane];
    const float cc = c_a[plane];
    const float ss = s_a[plane];
    const float tx = tx_a[plane];
    const float ty = ty_a[plane];

    // Fold normalized->pixel mapping: x = w*ax + h*bx + cx (align_corners=F):
    const float gstep = 2.0f / (float)(W_ - 1);
    const float k64 = (float)W_ * 0.5f;                  // 64
    const float ax =  cc * sc * gstep * k64;
    const float bx = -ss * sc * gstep * k64;
    const float cx = (tx - cc * sc + ss * sc + 1.0f) * k64 - 0.5f;
    const float ay =  ss * sc * gstep * k64;
    const float by =  cc * sc * gstep * k64;
    const float cy = (ty - ss * sc - cc * sc + 1.0f) * k64 - 0.5f;

    // Per-thread base pixel (h0 = tid>>7, w0 = tid&127); iteration adds
    // exactly 4 rows (512 threads / 128 cols): x_it = xb + it*dx4.
    const int h0 = tid >> 7;
    const int w0 = tid & (W_ - 1);
    const float xb = fmaf((float)w0, ax, fmaf((float)h0, bx, cx));
    const float yb = fmaf((float)w0, ay, fmaf((float)h0, by, cy));
    const float dx4 = 4.0f * bx;
    const float dy4 = 4.0f * by;

    __syncthreads();

    // ---- 32 px/thread in 8 batches of 4 pixels; ONE ds_read2_b32 per px ----
#pragma unroll
    for (int b4 = 0; b4 < 8; ++b4) {
        float wxv[4], wyv[4];
        unsigned int d0[4], d1[4];

        // phase A: addresses + issue all taps (1 ds_read2_b32 / px)
#pragma unroll
        for (int u = 0; u < 4; ++u) {
            const float it = (float)(b4 * 4 + u);
            float x = fmaf(it, dx4, xb);
            float y = fmaf(it, dy4, yb);
            x = fminf(fmaxf(x, 0.0f), (float)(W_ - 1));   // border padding
            y = fminf(fmaxf(y, 0.0f), (float)(H_ - 1));
            const float x0f = floorf(x);
            const float y0f = floorf(y);
            wxv[u] = x - x0f;
            wyv[u] = y - y0f;
            // record dword index, exact: y0f*129 + x0f <= 16511 < 2^24
            const int bi = (int)fmaf(y0f, (float)RS_, x0f);
            d0[u] = rec[bi];          // {v(y0,x0) lo, v(y0+1,x0) hi}
            d1[u] = rec[bi + 1];      // {v(y0,x1) lo, v(y0+1,x1) hi}
        }

        __builtin_amdgcn_sched_barrier(0);

        // phase B: decode + lerps + nontemporal coalesced stores
#pragma unroll
        for (int u = 0; u < 4; ++u) {
            const float v00 = __uint_as_float(d0[u] << 16);
            const float v10 = __uint_as_float(d0[u] & 0xFFFF0000u);
            const float v01 = __uint_as_float(d1[u] << 16);
            const float v11 = __uint_as_float(d1[u] & 0xFFFF0000u);
            const float top = v00 + wxv[u] * (v01 - v00);
            const float bot = v10 + wxv[u] * (v11 - v10);
            const int px = (b4 * 4 + u) * 512 + tid;
            __builtin_nontemporal_store(top + wyv[u] * (bot - top), &op[px]);
        }
    }
}

extern "C" void kernel_launch(void* const* d_in, const int* in_sizes, int n_in,
                              void* d_out, int out_size, void* d_ws, size_t ws_size,
                              hipStream_t stream) {
    const float* feature_map = (const float*)d_in[0];
    const float* para_code   = (const float*)d_in[1];
    const float* W1 = (const float*)d_in[2];
    const float* b1 = (const float*)d_in[3];
    const float* Ws = (const float*)d_in[4];
    const float* bs = (const float*)d_in[5];
    const float* Wr = (const float*)d_in[6];
    const float* br = (const float*)d_in[7];
    const float* Wt = (const float*)d_in[8];
    const float* bt = (const float*)d_in[9];
    float* out = (float*)d_out;

    // Workspace layout (floats): sc | c | s | tx | ty (each B_*D_)
    float* ws_f = (float*)d_ws;
    float* sc_a  = ws_f;
    float* c_a   = sc_a + B_ * D_;
    float* s_a   = c_a  + B_ * D_;
    float* tx_a  = s_a  + B_ * D_;
    float* ty_a  = tx_a + B_ * D_;

    k_params<<<dim3(B_, 2), PC_, 0, stream>>>(para_code, W1, b1, Ws, bs, Wr, br,
                                              Wt, bt, sc_a, c_a, s_a, tx_a, ty_a);
    k_sample<<<B_ * D_, 512, 0, stream>>>(feature_map, sc_a, c_a, s_a, tx_a, ty_a, out);
}

// Round 14
// 66.611 us; speedup vs baseline: 1.2336x; 1.2093x over previous
//
#include <hip/hip_runtime.h>
#include <math.h>

// Problem shape (fixed by reference setup_inputs):
//   feature_map: (B=8, D=256, H=128, W=128) fp32
//   para_code:   (8, 256)
//   W1 (256,256) b1(256) | Ws (256,256) bs(256) | Wr (256,256) br(256)
//   Wt (256,512) bt(512)
// Output: (8, 256, 128, 128) fp32

#define B_  8
#define D_  256
#define H_  128
#define W_  128
#define PC_ 256
#define PI_F 3.14159f
#define LPU_ 130  // padded bf16 LDS row stride (ushorts) = 65 dwords/row;
                  // 65 % 32 == 1 -> row-step gathers conflict-free.

// ---------------- Kernel 1: p = relu(para_code @ W1 + b1) -------------------
// 8 blocks x 1024 threads, 4-way k-split per output channel + LDS reduce.
// Replaces the old 2-phase k_params (16 blocks, 256-step serial chain,
// ~8-10us): p is the only cross-plane dependency; the 4 head dots are now
// computed inside k_sample per plane (hidden under staging).
__global__ __launch_bounds__(1024)
void k_p(const float* __restrict__ para, const float* __restrict__ W1,
         const float* __restrict__ b1, float* __restrict__ p_out) {
    __shared__ float red[1024];
    const int b = blockIdx.x;
    const int t = threadIdx.x;
    const int d = t & 255;
    const int kc = t >> 8;                  // 0..3
    float acc = 0.0f;
#pragma unroll 8
    for (int i = 0; i < 64; ++i) {
        const int k = kc * 64 + i;          // wave-uniform -> para is s-load
        acc = fmaf(para[b * PC_ + k], W1[k * PC_ + d], acc);
    }
    red[t] = acc;
    __syncthreads();
    if (t < 256) {
        const float v = red[t] + red[t + 256] + red[t + 512] + red[t + 768] + b1[t];
        p_out[b * PC_ + t] = fmaxf(v, 0.0f);
    }
}

// ------------- Kernel 2: heads + affine grid-sample (fused) -----------------
// Gather core = round-11 exactly (best measured): bf16 plane in padded LDS
// (33.5KB -> 4 blocks/CU, 32 waves/CU), 4x ds_read_u16 taps, 8 batches of 4
// px with sched_barrier(0) phase split. NEW: this plane's head params
// (scale, angle, trans) are computed HERE — 4 dot-256s over p[b] split
// across 512 threads (2 MAC each), wave shuffle-reduce, redundant
// transcendental finalize per thread. Weight-column reads (L3-resident)
// issue before the 64KB stage and hide under it; removes the old k_params
// serialization (~8-10us of un-overlapped latency) from the critical path.
__global__ __launch_bounds__(512, 8)
void k_sample(const float* __restrict__ fm,
              const float* __restrict__ p_ws,
              const float* __restrict__ Ws, const float* __restrict__ bs,
              const float* __restrict__ Wr, const float* __restrict__ br,
              const float* __restrict__ Wt, const float* __restrict__ bt,
              float* __restrict__ out) {
    __shared__ unsigned short lds[129 * LPU_];   // 33,540 B -> 4 blocks/CU
    __shared__ float red[8];

    const int plane = blockIdx.x;                // 0 .. B_*D_-1
    const int b = plane >> 8;                    // batch
    const int d = plane & 255;                   // channel (block-uniform)
    const float* __restrict__ img = fm + (size_t)plane * (H_ * W_);
    float* __restrict__ op = out + (size_t)plane * (H_ * W_);
    const int tid = threadIdx.x;
    const int lane = tid & 63;
    const int wid = tid >> 6;                    // 0..7

    // ---- head-dot partials: issue the small loads FIRST (hide under stage).
    // q = which dot (0:scale 1:angle 2:tx 3:ty), uniform per wave.
    float dp;
    {
        const int q = tid >> 7;                  // 0..3
        const int kh = tid & 127;                // k-pair index
        const float2 pk = ((const float2*)(p_ws + b * PC_))[kh];
        const float* __restrict__ Wq = (q == 0) ? Ws : (q == 1) ? Wr : Wt;
        const int stride = (q < 2) ? PC_ : 2 * PC_;
        const int col = (q < 2) ? d : (2 * d + (q & 1));
        const int k0 = kh * 2;
        dp = pk.x * Wq[k0 * stride + col] + pk.y * Wq[(k0 + 1) * stride + col];
    }

    // ---- stage plane -> bf16 padded LDS (float4 loads, packed b32 writes) --
    {
        const float4* __restrict__ src = (const float4*)img;
#pragma unroll
        for (int j = 0; j < 8; ++j) {
            const int e4 = j * 512 + tid;        // float4 index 0..4095
            const float4 v = src[e4];
            const int h = e4 >> 5;               // (e4*4) >> 7
            const int w = (e4 & 31) * 4;
            unsigned int lo, hi;
            {   // bf16 RNE pack
                unsigned int ux = __float_as_uint(v.x); ux += 0x7FFFu + ((ux >> 16) & 1u);
                unsigned int uy = __float_as_uint(v.y); uy += 0x7FFFu + ((uy >> 16) & 1u);
                unsigned int uz = __float_as_uint(v.z); uz += 0x7FFFu + ((uz >> 16) & 1u);
                unsigned int uw = __float_as_uint(v.w); uw += 0x7FFFu + ((uw >> 16) & 1u);
                lo = (ux >> 16) | (uy & 0xFFFF0000u);
                hi = (uz >> 16) | (uw & 0xFFFF0000u);
            }
            unsigned int* dst = (unsigned int*)&lds[h * LPU_ + w];
            dst[0] = lo;
            dst[1] = hi;
        }
    }
    // zero pads: col 128 of rows 0..128, all of row 128 (taps read x0+1 /
    // y0+1 unconditionally; their weights are exactly 0 at the border)
    if (tid < H_ + 1)  lds[tid * LPU_ + W_] = 0;
    if (tid < LPU_)    lds[H_ * LPU_ + tid] = 0;

    // ---- reduce head-dot partials: wave shuffle -> red[wid] ----
#pragma unroll
    for (int off = 32; off > 0; off >>= 1) dp += __shfl_down(dp, off);
    if (lane == 0) red[wid] = dp;

    __syncthreads();   // covers lds[] staging AND red[]

    // ---- finalize heads (redundant per thread; block-uniform scalars) ----
    const float as_ = red[0] + red[1] + bs[d];
    const float ar_ = red[2] + red[3] + br[d];
    const float t0_ = red[4] + red[5] + bt[2 * d];
    const float t1_ = red[6] + red[7] + bt[2 * d + 1];
    const float sc = 2.0f / (1.0f + expf(-as_));     // sigmoid * 2
    const float ang = tanhf(ar_) * PI_F;
    const float cc = cosf(ang);
    const float ss = sinf(ang);
    const float tx = tanhf(t0_);
    const float ty = tanhf(t1_);

    // Fold normalized->pixel mapping: x = w*ax + h*bx + cx (align_corners=F):
    const float gstep = 2.0f / (float)(W_ - 1);
    const float k64 = (float)W_ * 0.5f;                  // 64
    const float ax =  cc * sc * gstep * k64;
    const float bx = -ss * sc * gstep * k64;
    const float cx = (tx - cc * sc + ss * sc + 1.0f) * k64 - 0.5f;
    const float ay =  ss * sc * gstep * k64;
    const float by =  cc * sc * gstep * k64;
    const float cy = (ty - ss * sc - cc * sc + 1.0f) * k64 - 0.5f;

    // Per-thread base pixel (h0 = tid>>7, w0 = tid&127); iteration adds
    // exactly 4 rows (512 threads / 128 cols): x_it = xb + it*dx4.
    const int h0 = tid >> 7;
    const int w0 = tid & (W_ - 1);
    const float xb = fmaf((float)w0, ax, fmaf((float)h0, bx, cx));
    const float yb = fmaf((float)w0, ay, fmaf((float)h0, by, cy));
    const float dx4 = 4.0f * bx;
    const float dy4 = 4.0f * by;

    // ---- 32 px/thread in 8 batches of 4 pixels (round-11 core) ----
#pragma unroll
    for (int b4 = 0; b4 < 8; ++b4) {
        float wxv[4], wyv[4];
        unsigned short t00[4], t01[4], t10[4], t11[4];

        // phase A: addresses + issue all 16 u16 taps
#pragma unroll
        for (int u = 0; u < 4; ++u) {
            const float it = (float)(b4 * 4 + u);
            float x = fmaf(it, dx4, xb);
            float y = fmaf(it, dy4, yb);
            x = fminf(fmaxf(x, 0.0f), (float)(W_ - 1));   // border padding
            y = fminf(fmaxf(y, 0.0f), (float)(H_ - 1));
            const float x0f = floorf(x);
            const float y0f = floorf(y);
            wxv[u] = x - x0f;
            wyv[u] = y - y0f;
            // exact: y0f*130 + x0f <= 16768 < 2^24
            const int base = (int)fmaf(y0f, (float)LPU_, x0f);
            t00[u] = lds[base];
            t01[u] = lds[base + 1];           // weight 0 when x at border
            t10[u] = lds[base + LPU_];        // weight 0 when y at border
            t11[u] = lds[base + LPU_ + 1];
        }

        __builtin_amdgcn_sched_barrier(0);

        // phase B: decode + lerps + coalesced stores
#pragma unroll
        for (int u = 0; u < 4; ++u) {
            const float v00 = __uint_as_float((unsigned int)t00[u] << 16);
            const float v01 = __uint_as_float((unsigned int)t01[u] << 16);
            const float v10 = __uint_as_float((unsigned int)t10[u] << 16);
            const float v11 = __uint_as_float((unsigned int)t11[u] << 16);
            const int px = (b4 * 4 + u) * 512 + tid;
            const float top = v00 + wxv[u] * (v01 - v00);
            const float bot = v10 + wxv[u] * (v11 - v10);
            op[px] = top + wyv[u] * (bot - top);
        }
    }
}

extern "C" void kernel_launch(void* const* d_in, const int* in_sizes, int n_in,
                              void* d_out, int out_size, void* d_ws, size_t ws_size,
                              hipStream_t stream) {
    const float* feature_map = (const float*)d_in[0];
    const float* para_code   = (const float*)d_in[1];
    const float* W1 = (const float*)d_in[2];
    const float* b1 = (const float*)d_in[3];
    const float* Ws = (const float*)d_in[4];
    const float* bs = (const float*)d_in[5];
    const float* Wr = (const float*)d_in[6];
    const float* br = (const float*)d_in[7];
    const float* Wt = (const float*)d_in[8];
    const float* bt = (const float*)d_in[9];
    float* out = (float*)d_out;

    // Workspace: p (B_*PC_ floats)
    float* p_ws = (float*)d_ws;

    k_p<<<B_, 1024, 0, stream>>>(para_code, W1, b1, p_ws);
    k_sample<<<B_ * D_, 512, 0, stream>>>(feature_map, p_ws,
                                          Ws, bs, Wr, br, Wt, bt, out);
}